// Round 6
// baseline (6443.955 us; speedup 1.0000x reference)
//
#include <hip/hip_runtime.h>

#define N_CLOUDS 16
#define PTS      16384
#define M        4096
#define THREADS  512
#define NWAVES   8
#define PPT      32                 // consecutive points per thread
#define NPAIR    16                 // 16 v2f pairs per thread
#define SMEM_BYTES (NPAIR * THREADS * 16 + 64 + 32)

typedef float v2f __attribute__((ext_vector_type(2)));
typedef unsigned long long u64;
typedef unsigned int u32;

// One block per cloud; serial FPS.
// Round-6 restructure (rounds 3-5 proved the allocator will NOT keep 128+
// floats of loop state in VGPRs — it streams them at ~1500 cyc/iter):
//  - x,y coords live in LDS (128 KB, dynamic), layout [pair][tid] float4
//    {x0,x1,y0,y1}: one ds_read_b128/pair feeds pk math, conflict-free.
//  - z + dist in registers only (~100 VGPRs total: fits for real).
//  - value-only argmax: per pair one v_max3 into 2 partial maxes; wave
//    reduce is f32 DPP (12 inst, was 45 for u64); index recovered by a
//    candidate scan on the single wave holding the block max.
//  - winner z rides the atomicMin_u64 key (idx<<32 | z-bits): tie-safe
//    (smallest index wins both) and kills the 200-cyc global coord fetch;
//    winner x,y come from the LDS arrays (broadcast read).
//  - exact fp compares + contract-off math => bit-identical picks (absmax 0).

#define F24_X(X) X(0) X(1) X(2) X(3) X(4) X(5) X(6) X(7) X(8) X(9) X(10) X(11) \
                 X(12) X(13) X(14) X(15) X(16) X(17) X(18) X(19) X(20) X(21) X(22) X(23)
// QUAD(j0,j1,a,b,c): pairs j0=2m, j1=2m+1 from float4 f_a,f_b,f_c
// (points 4m..4m+3 = 12 floats: x0 y0 z0 x1 y1 z1 x2 y2 z2 x3 y3 z3)
#define QUADS_X(X) X(0,1,0,1,2)     X(2,3,3,4,5)      X(4,5,6,7,8)      X(6,7,9,10,11) \
                   X(8,9,12,13,14)  X(10,11,15,16,17) X(12,13,18,19,20) X(14,15,21,22,23)
#define PAIRS_X(X) X(0) X(1) X(2) X(3) X(4) X(5) X(6) X(7) \
                   X(8) X(9) X(10) X(11) X(12) X(13) X(14) X(15)

// f32 max-combine with DPP-shifted copy (old=0 = +0.0f, identity: dists >= 0)
#define DPP_FMAX(bd, CTRL) { \
        const int t_ = __builtin_amdgcn_update_dpp(0, __float_as_int(bd), (CTRL), 0xf, 0xf, false); \
        (bd) = fmaxf((bd), __int_as_float(t_)); }

__global__ __launch_bounds__(THREADS) void fps_kernel(
    const float* __restrict__ pos, int* __restrict__ out)
{
#pragma clang fp contract(off)
    extern __shared__ char smem[];
    float4* xy   = (float4*)smem;                            // [NPAIR*THREADS]
    float*  swv  = (float*)(smem + NPAIR * THREADS * 16);    // [2*NWAVES]
    u64*    mins = (u64*)(smem + NPAIR * THREADS * 16 + 64); // [4]

    const int cloud = blockIdx.x;
    const int tid   = threadIdx.x;
    const int base  = cloud * PTS;

    // ---- query = point 0 of cloud ----
    const float q0x = pos[(size_t)base * 3 + 0];
    const float q0y = pos[(size_t)base * 3 + 1];
    const float q0z = pos[(size_t)base * 3 + 2];
    v2f qx2 = {q0x, q0x}, qy2 = {q0y, q0y}, qz2 = {q0z, q0z};

    // ---- one-time load: 32 consecutive pts = 24 float4/thread ----
    const float4* pos4 = (const float4*)pos;
    const int fo = cloud * (PTS * 3 / 4) + tid * (PPT * 3 / 4);
#define LOADF(n) const float4 f##n = pos4[fo + (n)];
    F24_X(LOADF)
#undef LOADF

    // persistent register state: z pairs + dist pairs (64 floats)
#define DECL(j) v2f zz##j, dd##j; v2f XX##j, YY##j;
    PAIRS_X(DECL)
#undef DECL
#define REPACK(j0, j1, a, b, c) \
        XX##j0 = (v2f){f##a.x, f##a.w}; \
        YY##j0 = (v2f){f##a.y, f##b.x}; \
        zz##j0 = (v2f){f##a.z, f##b.y}; \
        XX##j1 = (v2f){f##b.z, f##c.y}; \
        YY##j1 = (v2f){f##b.w, f##c.z}; \
        zz##j1 = (v2f){f##c.x, f##c.w};
    QUADS_X(REPACK)
#undef REPACK

    float bd0 = -1.0f, bd1 = -1.0f;   // partial maxes: pairs 0-7 / 8-15
#define INITP(j, BD) { \
        xy[(j) * THREADS + tid] = make_float4(XX##j.x, XX##j.y, YY##j.x, YY##j.y); \
        v2f dx = XX##j - qx2; \
        v2f dy = YY##j - qy2; \
        v2f dz = zz##j - qz2; \
        v2f nd = (dx * dx + dy * dy) + dz * dz; \
        dd##j = nd; \
        BD = fmaxf(BD, fmaxf(nd.x, nd.y)); }
    INITP(0, bd0) INITP(1, bd0) INITP(2, bd0) INITP(3, bd0)
    INITP(4, bd0) INITP(5, bd0) INITP(6, bd0) INITP(7, bd0)
    INITP(8, bd1) INITP(9, bd1) INITP(10, bd1) INITP(11, bd1)
    INITP(12, bd1) INITP(13, bd1) INITP(14, bd1) INITP(15, bd1)
#undef INITP

    if (tid < 4)  mins[tid] = ~0ull;
    if (tid == 0) out[cloud * M] = base;   // first sample = point 0
    __syncthreads();                       // xy + mins visible to all

    const int wave = tid >> 6;
    const int lane = tid & 63;

    for (int i = 1; i < M; ++i) {
        const int p = i & 1;

        // ---- wave f32 max reduce via DPP; full max lands in lane 63 ----
        float bd = fmaxf(bd0, bd1);
        DPP_FMAX(bd, 0x111)   // row_shr:1
        DPP_FMAX(bd, 0x112)   // row_shr:2
        DPP_FMAX(bd, 0x114)   // row_shr:4
        DPP_FMAX(bd, 0x118)   // row_shr:8
        DPP_FMAX(bd, 0x142)   // row_bcast:15
        DPP_FMAX(bd, 0x143)   // row_bcast:31 -> lane 63 = wave max
        if (lane == 63) swv[p * NWAVES + wave] = bd;
        __syncthreads();

        // ---- block max from the 8 wave maxes (uniform) ----
        const float4 sa = ((const float4*)(swv + p * NWAVES))[0];
        const float4 sb = ((const float4*)(swv + p * NWAVES))[1];
        const float wv = fmaxf(fmaxf(fmaxf(sa.x, sa.y), fmaxf(sa.z, sa.w)),
                               fmaxf(fmaxf(sb.x, sb.y), fmaxf(sb.z, sb.w)));

        // ---- candidate scan: only the wave(s) holding wv; first candidate
        //      lane = smallest tid = smallest point index ----
        const bool c0 = (bd0 == wv);
        const bool c1 = (bd1 == wv);
        const u64 bal = __ballot(c0 || c1);
        if (bal != 0) {
            const int first = __ffsll(bal) - 1;
            if (lane == first) {
                int k = -1; float zs = 0.0f;
#define SCANJ(j) { if (dd##j.y == wv) { k = 2*(j) + 1; zs = zz##j.y; } \
                   if (dd##j.x == wv) { k = 2*(j);     zs = zz##j.x; } }
                if (c0) { SCANJ(7)  SCANJ(6)  SCANJ(5)  SCANJ(4)
                          SCANJ(3)  SCANJ(2)  SCANJ(1)  SCANJ(0) }
                else    { SCANJ(15) SCANJ(14) SCANJ(13) SCANJ(12)
                          SCANJ(11) SCANJ(10) SCANJ(9)  SCANJ(8) }
#undef SCANJ
                const u64 key = ((u64)(u32)(tid * PPT + k) << 32)
                              | (u64)__float_as_uint(zs);
                atomicMin(&mins[i & 3], key);
            }
        }
        __syncthreads();

        // ---- winner: idx + z from min-key; x,y from LDS (broadcast) ----
        const u64 wk = mins[i & 3];
        const int wi = (int)(wk >> 32);
        const float qz = __uint_as_float((u32)wk);
        const int wt = wi >> 5, kk = wi & 31, jj = kk >> 1, hh = kk & 1;
        const float4 w4 = xy[jj * THREADS + wt];
        const float qx = hh ? w4.y : w4.x;
        const float qy = hh ? w4.w : w4.z;
        if (tid == 0) {
            out[cloud * M + i] = base + wi;
            mins[(i + 2) & 3] = ~0ull;   // re-arm slot for iter i+2 (barrier-safe)
        }
        qx2 = (v2f){qx, qx}; qy2 = (v2f){qy, qy}; qz2 = (v2f){qz, qz};

        // ---- distance update + value-only partial maxes ----
        bd0 = -1.0f; bd1 = -1.0f;
#define UPD(j, BD) { \
        const float4 t4 = xy[(j) * THREADS + tid]; \
        const v2f xx = {t4.x, t4.y}; \
        const v2f yy = {t4.z, t4.w}; \
        v2f dx = xx - qx2; \
        v2f dy = yy - qy2; \
        v2f dz = zz##j - qz2; \
        v2f nd = (dx * dx + dy * dy) + dz * dz; \
        dd##j.x = fminf(dd##j.x, nd.x); \
        dd##j.y = fminf(dd##j.y, nd.y); \
        BD = fmaxf(BD, fmaxf(dd##j.x, dd##j.y)); }
        UPD(0, bd0) UPD(1, bd0) UPD(2, bd0) UPD(3, bd0)
        UPD(4, bd0) UPD(5, bd0) UPD(6, bd0) UPD(7, bd0)
        UPD(8, bd1) UPD(9, bd1) UPD(10, bd1) UPD(11, bd1)
        UPD(12, bd1) UPD(13, bd1) UPD(14, bd1) UPD(15, bd1)
#undef UPD
    }
}

extern "C" void kernel_launch(void* const* d_in, const int* in_sizes, int n_in,
                              void* d_out, int out_size, void* d_ws, size_t ws_size,
                              hipStream_t stream) {
    const float* pos = (const float*)d_in[0];
    int* out = (int*)d_out;
    static bool attr_set = false;   // idempotent host-side attr, not a stream op
    hipFuncSetAttribute((const void*)fps_kernel,
                        hipFuncAttributeMaxDynamicSharedMemorySize, SMEM_BYTES);
    (void)attr_set;
    fps_kernel<<<N_CLOUDS, THREADS, SMEM_BYTES, stream>>>(pos, out);
}